// Round 11
// baseline (193.993 us; speedup 1.0000x reference)
//
#include <hip/hip_runtime.h>
#include <math.h>

typedef unsigned int  u32;
typedef unsigned short u16;
typedef unsigned char u8;
typedef short bf16x8 __attribute__((ext_vector_type(8)));   // 8 bf16 = 4 VGPRs
typedef float f32x4  __attribute__((ext_vector_type(4)));
typedef float f32x2  __attribute__((ext_vector_type(2)));

// Problem constants (match reference)
#define NN    50000
#define NE    800000
#define ET    (NE + NN)     // edges + self loops = 850000
#define IND   128
#define HIDD  128
#define NH    8
#define OD    64
#define SLOPE 0.2f

// Binned counting sort parameters. Self-loops are NOT staged (deterministic,
// k_place inserts them directly). Rows are padded to 8-edge groups with a
// NULL node (id NN, weight exactly 0) -> no tail loops, uint4 packs.
#define NB    196           // buckets of 256 nodes: ceil(50000/256)
#define EPB   4096          // edges per binning block
#define NBB   ((NE + EPB - 1) / EPB)   // 196 binning blocks (random edges only)
#define LCAP  64            // LDS cap per (block,bucket): mean 21, +9.4 sigma
#define CAPB  5120          // global cap per bucket: mean 4082, +13 sigma
#define CPAD  16            // counter stride in ints (64 B = own cache line)
#define BSTRIDE 7168        // fixed padded bucket stride (pad8)

// Extended GEMM widths: alpha reductions folded in as extra columns.
#define W1EXT 144
#define W2EXT 80
#define WPB   112           // wprep blocks (covers (W1EXT+W2EXT)*128 = 28672)
#define G1B   391           // gemm blocks: ceil(50000/128)

// h1 fp8 2-way channel slice: slice s holds channels 64s..64s+63 (heads
// 4s..4s+3). Slice table = (NN+1) rows x 64 B = 3.2 MB -> fits 4 MiB per-XCD
// L2. agg1 wave = (node, slice); slice = blockIdx&1 -> slice parity matches
// XCD parity under the %8 round-robin dispatch (perf heuristic only).
#define SSTR ((size_t)(NN + 1) * 16)    // h1 slice stride, u32 units (64 B/row)
#define ASTR ((size_t)(NN + 1) * 4)     // as1/ad1 slice stride, f32 units

// bf16 round-to-nearest-even, returns low 16 bits
__device__ __forceinline__ u32 bf16rne(float f) {
    u32 u = __float_as_uint(f);
    return (u + 0x7fffu + ((u >> 16) & 1u)) >> 16;
}

// leaky_relu(s) == max(s, SLOPE*s) for 0 < SLOPE < 1
#define LR(s) fmaxf((s), SLOPE * (s))

// extract u16 element e (0..7) of a uint4 pack without address-of (no scratch)
__device__ __forceinline__ u32 sel8(uint4 p, int e) {
    const u32 c = (e & 4) ? ((e & 2) ? p.w : p.z) : ((e & 2) ? p.y : p.x);
    return (e & 1) ? (c >> 16) : (c & 0xffffu);
}

// ---------------------------------------------------------------------------
// Fused launch 1: blocks 0..NBB-1 = edge binning (LDS-staged radix partition);
// blocks NBB.. = weight prep (extended transposed bf16 weights + null inits).
// cnt is zeroed by hipMemsetAsync before this launch (bin atomics need it).
// ---------------------------------------------------------------------------
__global__ __launch_bounds__(256) void k_prep_bin(
    const int* __restrict__ ei, int* __restrict__ cnt, u32* __restrict__ staging,
    const float* __restrict__ W1, const float* __restrict__ W2,
    const float* __restrict__ as1w, const float* __restrict__ ad1w,
    const float* __restrict__ as2w, const float* __restrict__ ad2w,
    u16* __restrict__ Wt1, u16* __restrict__ Wt2,
    u32* __restrict__ h1s8, float* __restrict__ as1s, float* __restrict__ as2)
{
    __shared__ u32 lbuf[NB * LCAP];   // 50176 B (bin path only)
    __shared__ int lcnt[NB];
    __shared__ int gbase[NB];
    const int t = threadIdx.x;

    if (blockIdx.x >= NBB) {
        // ---- weight-prep path ----
        const int i = (blockIdx.x - NBB) * 256 + t;
        if (i < 32)                                        // null rows, both slices
            h1s8[(size_t)(i >> 4) * SSTR + (size_t)NN * 16 + (i & 15)] = 0;
        if (i < 8)                                         // null alpha_src L1
            as1s[(size_t)(i >> 2) * ASTR + (size_t)NN * 4 + (i & 3)] = -1e30f;
        if (i == 8) as2[NN] = -1e30f;                      // null alpha_src L2

        if (i < W1EXT * 128) {
            const int j = i >> 7, k = i & 127;
            float v;
            if (j < 128) {
                v = W1[k * 128 + j];
            } else if (j < 136) {
                const int h = j - 128;
                v = 0.f;
                for (int c = 0; c < 16; ++c)
                    v += W1[k * 128 + h * 16 + c] * as1w[h * 16 + c];
            } else {
                const int h = j - 136;
                v = 0.f;
                for (int c = 0; c < 16; ++c)
                    v += W1[k * 128 + h * 16 + c] * ad1w[h * 16 + c];
            }
            Wt1[j * 128 + k] = (u16)bf16rne(v);
        } else if (i < W1EXT * 128 + W2EXT * 128) {
            const int i2 = i - W1EXT * 128;
            const int j = i2 >> 7, k = i2 & 127;
            float v = 0.f;
            if (j < 64) {
                v = W2[k * 64 + j];
            } else if (j == 64) {
                for (int c = 0; c < 64; ++c) v += W2[k * 64 + c] * as2w[c];
            } else if (j == 65) {
                for (int c = 0; c < 64; ++c) v += W2[k * 64 + c] * ad2w[c];
            }
            Wt2[j * 128 + k] = (u16)bf16rne(v);
        }
        return;
    }

    // ---- binning path ----
    const int e0 = blockIdx.x * EPB;
    for (int i = t; i < NB; i += 256) lcnt[i] = 0;
    __syncthreads();

    for (int i = t; i < EPB; i += 256) {
        const int e = e0 + i;
        if (e >= NE) break;
        const int src = ei[e];
        const int dst = ei[NE + e];
        const int b = dst >> 8;
        const int p = atomicAdd(&lcnt[b], 1);       // LDS atomic (cheap)
        lbuf[b * LCAP + p] = ((u32)(dst & 255) << 16) | (u32)src;
    }
    __syncthreads();

    for (int i = t; i < NB; i += 256)
        gbase[i] = atomicAdd(&cnt[i * CPAD], lcnt[i]);
    __syncthreads();

    // flush: thread = bucket; sequential stores -> lines merge in L2
    for (int b = t; b < NB; b += 256) {
        const int n = lcnt[b];
        const int gb = gbase[b];
        u32* dstp = staging + (size_t)b * CAPB + gb;
        const u32* srcp = lbuf + b * LCAP;
        for (int j = 0; j < n; ++j) dstp[j] = srcp[j];
    }
}

// ---------------------------------------------------------------------------
// Fused launch 2: blocks 0..NB-1 = k_place (CSR build, 8-padded rows, fixed
// bucket base); blocks NB.. = MFMA GEMM1 [h1|as1|ad1] = x @ W1ext, 128 rows x
// 8 waves. h1 stored FP8 e4m3 in TWO channel slices (64 B/row each):
// fragments -> swizzled LDS bytes -> coalesced uint4 stores. Alphas sliced.
// ---------------------------------------------------------------------------
__global__ __launch_bounds__(512) void k_place_gemm1(
    const int* __restrict__ cnt, const u32* __restrict__ staging,
    int* __restrict__ rowptr, int* __restrict__ rowend,
    u16* __restrict__ sorted16,
    const float* __restrict__ x, const u16* __restrict__ Wt1,
    u32* __restrict__ h1s8, float* __restrict__ as1s, float* __restrict__ ad1s)
{
    __shared__ u32 xb[128 * 64];     // 32 KB (gemm: A tile, then C staging)
    __shared__ u32 Wb[W1EXT * 64];   // 36 KB
    const int tid = threadIdx.x;

    if (blockIdx.x < NB) {
        // ---- place path (512 threads; LDS carved from xb) ----
        int* hist = (int*)xb;
        int* cur  = hist + 256;
        int* scan = cur + 256;
        const int b = blockIdx.x;
        const int tot = cnt[b * CPAD];
        const int base = b * BSTRIDE;

        if (tid < 256) hist[tid] = ((b * 256 + tid) < NN) ? 1 : 0;  // self-loop
        __syncthreads();

        for (int i = tid; i < tot; i += 512)
            atomicAdd(&hist[staging[(size_t)b * CAPB + i] >> 16], 1);
        __syncthreads();

        if (tid < 256) scan[tid] = (hist[tid] + 7) & ~7;   // pad8 counts
        __syncthreads();
        for (int off = 1; off < 256; off <<= 1) {
            int v = 0;
            if (tid < 256 && tid >= off) v = scan[tid - off];
            __syncthreads();
            if (tid < 256) scan[tid] += v;
            __syncthreads();
        }
        if (tid < 256) {
            const int padded = (hist[tid] + 7) & ~7;
            const int excl = (tid == 0) ? 0 : scan[tid - 1];
            const int node = b * 256 + tid;
            if (node < NN) {
                rowptr[node] = base + excl;
                rowend[node] = base + excl + padded;       // padded end
                sorted16[base + excl] = (u16)node;         // self-loop first
                for (int j = hist[tid]; j < padded; ++j)   // null-pad tail
                    sorted16[base + excl + j] = (u16)NN;
                cur[tid] = excl + 1;
            } else {
                cur[tid] = excl;
            }
        }
        __syncthreads();
        for (int i = tid; i < tot; i += 512) {
            const u32 v = staging[(size_t)b * CAPB + i];
            const int pos = atomicAdd(&cur[v >> 16], 1);
            sorted16[base + pos] = (u16)(v & 0xffffu);
        }
        return;
    }

    // ---- gemm1 path ----
    const int row0 = (blockIdx.x - NB) * 128;

    {   // stage Wb from Wt1 (bf16 [j][k]): 2304 chunks over 512 threads
        const uint4* Wt = (const uint4*)Wt1;
        for (int p = 0; p < 5; ++p) {
            const int id = p * 512 + tid;
            if (id < W1EXT * 16) {
                const int n = id >> 4, c = id & 15;
                *(uint4*)(Wb + n * 64 + ((c ^ (n & 15)) << 2)) = Wt[n * 16 + c];
            }
        }
    }
    for (int p = 0; p < 4; ++p) {    // 2048 chunks of xb
        const int id = p * 512 + tid;
        const int m = id >> 4, c = id & 15;
        const int row = row0 + m;
        uint4 v = make_uint4(0, 0, 0, 0);
        if (row < NN) {
            const float4 f0 = *(const float4*)(x + (size_t)row * 128 + c * 8);
            const float4 f1 = *(const float4*)(x + (size_t)row * 128 + c * 8 + 4);
            v.x = bf16rne(f0.x) | (bf16rne(f0.y) << 16);
            v.y = bf16rne(f0.z) | (bf16rne(f0.w) << 16);
            v.z = bf16rne(f1.x) | (bf16rne(f1.y) << 16);
            v.w = bf16rne(f1.z) | (bf16rne(f1.w) << 16);
        }
        *(uint4*)(xb + m * 64 + ((c ^ (m & 15)) << 2)) = v;
    }
    __syncthreads();

    const int w = tid >> 6, lane = tid & 63;   // w = 0..7 -> rows 16w..16w+15
    const int nl = lane & 15, quad = lane >> 4;
    f32x4 acc[9] = {};
    for (int kk = 0; kk < 4; ++kk) {
        const int cm = kk * 4 + quad;
        const bf16x8 a = *(const bf16x8*)(xb + (16 * w + nl) * 64 + ((cm ^ nl) << 2));
#pragma unroll
        for (int tn = 0; tn < 9; ++tn) {
            const bf16x8 b = *(const bf16x8*)(Wb + (16 * tn + nl) * 64 + ((cm ^ nl) << 2));
            acc[tn] = __builtin_amdgcn_mfma_f32_16x16x32_bf16(a, b, acc[tn], 0, 0, 0);
        }
    }

    __syncthreads();                 // all xb reads done -> reuse as C staging
    {   // h1 fragments -> fp8 bytes in LDS [128 rows][8 chunks of 16B],
        // chunk index XOR-swizzled by (row>>2)&7 -> <=4-way bank conflict
        u8* h1ld = (u8*)xb;
#pragma unroll
        for (int tn = 0; tn < 8; ++tn) {
#pragma unroll
            for (int r = 0; r < 4; ++r) {
                const int row = 16 * w + quad * 4 + r;
                const u32 pk = __builtin_amdgcn_cvt_pk_fp8_f32(
                    acc[tn][r], 0.f, 0u, false);   // byte0 = fp8(acc)
                h1ld[row * 128 + ((tn ^ ((row >> 2) & 7)) << 4) + nl] = (u8)pk;
            }
        }
    }
#pragma unroll
    for (int r = 0; r < 4; ++r) {    // tile 8: cols 128..143 = [as1 | ad1]
        const int row = row0 + 16 * w + quad * 4 + r;
        if (row < NN) {
            const float v = acc[8][r];
            if (nl < 8)
                as1s[(size_t)(nl >> 2) * ASTR + (size_t)row * 4 + (nl & 3)] = v;
            else {
                const int h = nl - 8;
                ad1s[(size_t)(h >> 2) * ASTR + (size_t)row * 4 + (h & 3)] = v;
            }
        }
    }
    __syncthreads();
    // coalesced fp8 h1 store into slices: chunk c (16B) -> slice c>>2
    for (int p = 0; p < 2; ++p) {
        const int id = p * 512 + tid;
        const int row = id >> 3, c = id & 7;
        const int grow = row0 + row;
        if (grow < NN)
            ((uint4*)h1s8)[(size_t)(c >> 2) * ((size_t)(NN + 1) * 4) +
                           (size_t)grow * 4 + (c & 3)]
                = ((const uint4*)xb)[row * 8 + (c ^ ((row >> 2) & 7))];
    }
}

// ---------------------------------------------------------------------------
// MFMA GEMM2: [h2 | as2 | ad2] = act2 @ W2ext (50000x128 @ 128x80).
// h2 stays bf16 (feeds the final logits directly).
// ---------------------------------------------------------------------------
__global__ __launch_bounds__(512) void k_gemm2(
    const u32* __restrict__ act2b, const u16* __restrict__ Wt2,
    u16* __restrict__ h2s, float* __restrict__ as2, float* __restrict__ ad2)
{
    __shared__ u32 xb[128 * 64];     // 32 KB
    __shared__ u32 Wb[W2EXT * 64];   // 20 KB
    const int tid = threadIdx.x;
    const int row0 = blockIdx.x * 128;

    {   // stage Wb from Wt2: 1280 chunks over 512 threads
        const uint4* Wt = (const uint4*)Wt2;
        for (int p = 0; p < 3; ++p) {
            const int id = p * 512 + tid;
            if (id < W2EXT * 16) {
                const int n = id >> 4, c = id & 15;
                *(uint4*)(Wb + n * 64 + ((c ^ (n & 15)) << 2)) = Wt[n * 16 + c];
            }
        }
    }
    for (int p = 0; p < 4; ++p) {    // 2048 chunks of xb (bf16 row-major input)
        const int id = p * 512 + tid;
        const int m = id >> 4, c = id & 15;
        const int row = row0 + m;
        uint4 v = make_uint4(0, 0, 0, 0);
        if (row < NN) v = ((const uint4*)act2b)[(size_t)row * 16 + c];
        *(uint4*)(xb + m * 64 + ((c ^ (m & 15)) << 2)) = v;
    }
    __syncthreads();

    const int w = tid >> 6, lane = tid & 63;
    const int nl = lane & 15, quad = lane >> 4;
    f32x4 acc[5] = {};
    for (int kk = 0; kk < 4; ++kk) {
        const int cm = kk * 4 + quad;
        const bf16x8 a = *(const bf16x8*)(xb + (16 * w + nl) * 64 + ((cm ^ nl) << 2));
#pragma unroll
        for (int tn = 0; tn < 5; ++tn) {
            const bf16x8 b = *(const bf16x8*)(Wb + (16 * tn + nl) * 64 + ((cm ^ nl) << 2));
            acc[tn] = __builtin_amdgcn_mfma_f32_16x16x32_bf16(a, b, acc[tn], 0, 0, 0);
        }
    }

    __syncthreads();                 // all xb reads done -> reuse as C staging
    {   // h2 fragments -> LDS row-major u16 [128][64]
        u16* h2ld = (u16*)xb;
#pragma unroll
        for (int tn = 0; tn < 4; ++tn) {
#pragma unroll
            for (int r = 0; r < 4; ++r) {
                const int row = 16 * w + quad * 4 + r;
                h2ld[row * 64 + 16 * tn + nl] = (u16)bf16rne(acc[tn][r]);
            }
        }
    }
#pragma unroll
    for (int r = 0; r < 4; ++r) {    // tile 4: col 64 = as2, col 65 = ad2
        const int row = row0 + 16 * w + quad * 4 + r;
        if (row < NN) {
            const float v = acc[4][r];
            if (nl == 0) as2[row] = v;
            else if (nl == 1) ad2[row] = v;
        }
    }
    __syncthreads();
    // coalesced h2 store: 1024 uint4 chunks, 2 per thread
    for (int p = 0; p < 2; ++p) {
        const int id = p * 512 + tid;
        const int row = id >> 3, c = id & 7;
        const int grow = row0 + row;
        if (grow < NN)
            ((uint4*)h2s)[(size_t)grow * 8 + c] = ((const uint4*)xb)[row * 8 + c];
    }
}

// ---------------------------------------------------------------------------
// Aggregation layer 1 (fp8, 2-way channel slice, L2-local): wave = (node,
// slice of 64 channels = 4 heads). slice = blockIdx&1 -> XCD parity keeps the
// 3.2 MB slice table L2-resident. Per 8-edge group: 1 uint4 pack, 1 sliced
// as1 gather + exp (lane (4e+h) computes w(e, slice-head h); dup on upper
// half), FOUR u16 loads (load i gathers edges 2i / 2i+1 on the two wave
// halves; lane&31 = channel pair) -> 2-deep pipeline = 8 loads / 16 lines in
// flight, 1 bpermute + fp8 cvt per load. shfl_xor(32) merges edge halves.
// ---------------------------------------------------------------------------
#define PG1(KK, G, WJ) do {                                                   \
    const uint4 p = *(const uint4*)(sorted16 + (KK));                         \
    const u32 se = sel8(p, eidx);                                             \
    WJ = __expf(LR(asl[(size_t)se * 4 + ehead] + adeh));                      \
    _Pragma("unroll") for (int i = 0; i < 4; ++i) {                           \
        const u32 si = sel8(p, 2 * i + half);                                 \
        G[i] = h1u[(size_t)si * 32 + chp]; }                                  \
} while (0)

#define CONS1(G, WJ) do {                                                     \
    _Pragma("unroll") for (int i = 0; i < 4; ++i) {                           \
        const float wv = __uint_as_float((u32)__builtin_amdgcn_ds_bpermute(   \
            bpb + 32 * i, (int)__float_as_uint(WJ)));                         \
        const f32x2 f = __builtin_amdgcn_cvt_pk_f32_fp8((u32)G[i], false);    \
        acc0 += wv * f.x; acc1 += wv * f.y; den += wv; }                      \
} while (0)

__global__ __launch_bounds__(256) void k_agg1(
    const int* __restrict__ rowptr, const int* __restrict__ rowend,
    const u16* __restrict__ sorted16,
    const u16* __restrict__ h1u16, const float* __restrict__ as1s,
    const float* __restrict__ ad1s,
    u32* __restrict__ act2b)
{
    const int b = blockIdx.x;
    const int slice = b & 1;                     // XCD-parity slice select
    const int node = (b >> 1) * 4 + (threadIdx.x >> 6);
    const int lane = threadIdx.x & 63;
    const int half = lane >> 5;                  // gather: which edge of a pair
    const int chp  = lane & 31;                  // channel pair within slice
    const int myhead = chp >> 3;                 // slice-local head 0..3
    const int ehead = lane & 3;                  // exp role: slice-local head
    const int eidx  = (lane >> 2) & 7;           // exp role: edge (dup top half)
    const int bpb   = ((half << 2) | myhead) << 2;
    const float* asl = as1s + (size_t)slice * ASTR;
    const float adeh = ad1s[(size_t)slice * ASTR + (size_t)node * 4 + ehead];
    const u16* h1u = h1u16 + (size_t)slice * (size_t)(NN + 1) * 32;
    const int k0 = rowptr[node], kend = rowend[node];   // multiple of 8, >=8
    float acc0 = 0.f, acc1 = 0.f, den = 0.f;
    u16 gA[4], gB[4];
    float wA, wB;

    PG1(k0, gA, wA);
    int k = k0 + 8;
    while (k + 16 <= kend) {
        PG1(k, gB, wB);      CONS1(gA, wA);
        PG1(k + 8, gA, wA);  CONS1(gB, wB);
        k += 16;
    }
    if (k < kend) {
        PG1(k, gB, wB);  CONS1(gA, wA);  CONS1(gB, wB);
    } else {
        CONS1(gA, wA);
    }

    // merge the two edge-halves (lanes l and l^32 share channel pair + head)
    acc0 += __shfl_xor(acc0, 32);
    acc1 += __shfl_xor(acc1, 32);
    den  += __shfl_xor(den, 32);

    const float inv = 1.f / den;                 // self-loop => den > 0
    float v0 = acc0 * inv, v1 = acc1 * inv;
    v0 = v0 > 0.f ? v0 : expm1f(v0);             // ELU
    v1 = v1 > 0.f ? v1 : expm1f(v1);
    if (lane < 32)                               // 32 lanes x 4 B = 128 B slice
        act2b[(size_t)node * 64 + slice * 32 + chp] =
            bf16rne(v0) | (bf16rne(v1) << 16);
}

// ---------------------------------------------------------------------------
// Aggregation layer 2 (narrow) + log_softmax: one node per wave, lane =
// channel. Lane l computes the weight for edge (l&7) of the group (one exp
// instr per 8 edges); bpermute broadcasts. uint4 packs + 2-stage pipeline.
// ---------------------------------------------------------------------------
#define PG2(KK, S, G, WJ) do {                                                \
    const uint4 p = *(const uint4*)(sorted16 + (KK));                         \
    S[0] = p.x & 0xffffu; S[1] = p.x >> 16;                                   \
    S[2] = p.y & 0xffffu; S[3] = p.y >> 16;                                   \
    S[4] = p.z & 0xffffu; S[5] = p.z >> 16;                                   \
    S[6] = p.w & 0xffffu; S[7] = p.w >> 16;                                   \
    const u32 sj = sel8(p, lane & 7);                                         \
    WJ = __expf(LR(as2[sj] + adv));                                           \
    _Pragma("unroll") for (int j = 0; j < 8; ++j)                             \
        G[j] = h2s[S[j] * 64 + lane];                                         \
} while (0)

#define CONS2(G, WJ) do {                                                     \
    _Pragma("unroll") for (int j = 0; j < 8; ++j) {                           \
        const float wv = __uint_as_float((u32)__builtin_amdgcn_ds_bpermute(   \
            j << 2, (int)__float_as_uint(WJ)));                               \
        acc += wv * __uint_as_float(((u32)G[j]) << 16);                       \
        den += wv; }                                                          \
} while (0)

__global__ __launch_bounds__(256) void k_agg2(
    const int* __restrict__ rowptr, const int* __restrict__ rowend,
    const u16* __restrict__ sorted16,
    const u16* __restrict__ h2s, const float* __restrict__ as2,
    const float* __restrict__ ad2,
    float* __restrict__ out)
{
    const int node = blockIdx.x * 4 + (threadIdx.x >> 6);
    const int lane = threadIdx.x & 63;
    const float adv = ad2[node];
    const int k0 = rowptr[node], kend = rowend[node];
    float acc = 0.f, den = 0.f;
    u32 sA[8], sB[8];
    u16 gA[8], gB[8];
    float wA, wB;

    PG2(k0, sA, gA, wA);
    int k = k0 + 8;
    while (k + 16 <= kend) {
        PG2(k, sB, gB, wB);      CONS2(gA, wA);
        PG2(k + 8, sA, gA, wA);  CONS2(gB, wB);
        k += 16;
    }
    if (k < kend) {
        PG2(k, sB, gB, wB);  CONS2(gA, wA);  CONS2(gB, wB);
    } else {
        CONS2(gA, wA);
    }

    const float v = acc / den;
    float m = v;
    for (int kk = 1; kk < 64; kk <<= 1) m = fmaxf(m, __shfl_xor(m, kk));
    float se = __expf(v - m);
    for (int kk = 1; kk < 64; kk <<= 1) se += __shfl_xor(se, kk);
    out[node * 64 + lane] = v - m - logf(se);
}

// ---------------------------------------------------------------------------
// Workspace layout (u32 units, 64B-aligned chunks).
// ---------------------------------------------------------------------------
extern "C" void kernel_launch(void* const* d_in, const int* in_sizes, int n_in,
                              void* d_out, int out_size, void* d_ws, size_t ws_size,
                              hipStream_t stream)
{
    (void)in_sizes; (void)n_in; (void)out_size; (void)ws_size;
    const float* x    = (const float*)d_in[0];
    const int*   ei   = (const int*)d_in[1];
    const float* W1   = (const float*)d_in[2];
    const float* as1w = (const float*)d_in[3];
    const float* ad1w = (const float*)d_in[4];
    const float* W2   = (const float*)d_in[6];
    const float* as2w = (const float*)d_in[7];
    const float* ad2w = (const float*)d_in[8];
    float* out = (float*)d_out;

    u32* ws = (u32*)d_ws;
    size_t o = 0;
    auto take = [&](size_t n) { size_t r = o; o += (n + 15) & ~(size_t)15; return r; };

    u32*   h1s8     = ws + take(2 * SSTR);                 // 2 fp8 slices, 64 B rows
    float* as1s     = (float*)(ws + take(2 * ASTR));       // 2 slices x 4 heads
    float* ad1s     = (float*)(ws + take(2 * ASTR));
    u32*   act2b    = ws + take((size_t)64 * NN);          // bf16x2 packed
    float* as2      = (float*)(ws + take(NN + 1));
    float* ad2      = (float*)(ws + take(NN));
    int*   rowptr   = (int*)(ws + take(NN));
    int*   rowend   = (int*)(ws + take(NN));
    u16*   sorted16 = (u16*)(ws + take(((size_t)NB * BSTRIDE + 1) / 2));
    u32*   staging  = ws + take((size_t)NB * CAPB);
    int*   cnt      = (int*)(ws + take(NB * CPAD));
    u16*   Wt1      = (u16*)(ws + take((size_t)W1EXT * 128 / 2));
    u16*   Wt2      = (u16*)(ws + take((size_t)W2EXT * 128 / 2));
    u16*   h1u16    = (u16*)h1s8;          // u16 (channel-pair) view for agg1
    u16*   h2s      = (u16*)h1s8;          // alias (h1 dead after agg1)

    hipMemsetAsync(cnt, 0, NB * CPAD * sizeof(int), stream);

    k_prep_bin<<<NBB + WPB, 256, 0, stream>>>(
        ei, cnt, staging, W1, W2, as1w, ad1w, as2w, ad2w,
        Wt1, Wt2, h1s8, as1s, as2);

    k_place_gemm1<<<NB + G1B, 512, 0, stream>>>(
        cnt, staging, rowptr, rowend, sorted16, x, Wt1, h1s8, as1s, ad1s);

    k_agg1<<<NN / 2, 256, 0, stream>>>(rowptr, rowend, sorted16, h1u16, as1s, ad1s, act2b);
    k_gemm2<<<G1B, 512, 0, stream>>>(act2b, Wt2, h2s, as2, ad2);
    k_agg2<<<NN / 4, 256, 0, stream>>>(rowptr, rowend, sorted16, h2s, as2, ad2, out);
}

// Round 12
// 174.718 us; speedup vs baseline: 1.1103x; 1.1103x over previous
//
#include <hip/hip_runtime.h>
#include <math.h>

typedef unsigned int  u32;
typedef unsigned short u16;
typedef unsigned char u8;
typedef short bf16x8 __attribute__((ext_vector_type(8)));   // 8 bf16 = 4 VGPRs
typedef float f32x4  __attribute__((ext_vector_type(4)));
typedef float f32x2  __attribute__((ext_vector_type(2)));

// Problem constants (match reference)
#define NN    50000
#define NE    800000
#define ET    (NE + NN)     // edges + self loops = 850000
#define IND   128
#define HIDD  128
#define NH    8
#define OD    64
#define SLOPE 0.2f

// Binned counting sort parameters. Self-loops are NOT staged (deterministic,
// k_place inserts them directly). Rows are padded to 8-edge groups with a
// NULL node (id NN, weight exactly 0) -> no tail loops, uint4 packs.
#define NB    196           // buckets of 256 nodes: ceil(50000/256)
#define EPB   4096          // edges per binning block
#define NBB   ((NE + EPB - 1) / EPB)   // 196 binning blocks (random edges only)
#define LCAP  64            // LDS cap per (block,bucket): mean 21, +9.4 sigma
#define CAPB  5120          // global cap per bucket: mean 4082, +13 sigma
#define CPAD  16            // counter stride in ints (64 B = own cache line)
#define BSTRIDE 7168        // fixed padded bucket stride (pad8)

// Extended GEMM widths: alpha reductions folded in as extra columns.
#define W1EXT 144
#define W2EXT 80
#define WPB   112           // wprep blocks (covers (W1EXT+W2EXT)*128 = 28672)
#define G1B   391           // gemm blocks: ceil(50000/128)

// bf16 round-to-nearest-even, returns low 16 bits
__device__ __forceinline__ u32 bf16rne(float f) {
    u32 u = __float_as_uint(f);
    return (u + 0x7fffu + ((u >> 16) & 1u)) >> 16;
}

// leaky_relu(s) == max(s, SLOPE*s) for 0 < SLOPE < 1
#define LR(s) fmaxf((s), SLOPE * (s))

// ---------------------------------------------------------------------------
// Fused launch 1: blocks 0..NBB-1 = edge binning (LDS-staged radix partition);
// blocks NBB.. = weight prep (extended transposed bf16 weights + null inits).
// cnt is zeroed by hipMemsetAsync before this launch (bin atomics need it).
// ---------------------------------------------------------------------------
__global__ __launch_bounds__(256) void k_prep_bin(
    const int* __restrict__ ei, int* __restrict__ cnt, u32* __restrict__ staging,
    const float* __restrict__ W1, const float* __restrict__ W2,
    const float* __restrict__ as1w, const float* __restrict__ ad1w,
    const float* __restrict__ as2w, const float* __restrict__ ad2w,
    u16* __restrict__ Wt1, u16* __restrict__ Wt2,
    u32* __restrict__ h1f8, float* __restrict__ as1, float* __restrict__ as2)
{
    __shared__ u32 lbuf[NB * LCAP];   // 50176 B (bin path only)
    __shared__ int lcnt[NB];
    __shared__ int gbase[NB];
    const int t = threadIdx.x;

    if (blockIdx.x >= NBB) {
        // ---- weight-prep path ----
        const int i = (blockIdx.x - NBB) * 256 + t;
        if (i < 32) h1f8[(size_t)NN * 32 + i] = 0;         // null h1 row (fp8 0)
        if (i < 8)  as1[(size_t)NH * NN + i] = -1e30f;     // null alpha_src L1
        if (i == 8) as2[NN] = -1e30f;                      // null alpha_src L2

        if (i < W1EXT * 128) {
            const int j = i >> 7, k = i & 127;
            float v;
            if (j < 128) {
                v = W1[k * 128 + j];
            } else if (j < 136) {
                const int h = j - 128;
                v = 0.f;
                for (int c = 0; c < 16; ++c)
                    v += W1[k * 128 + h * 16 + c] * as1w[h * 16 + c];
            } else {
                const int h = j - 136;
                v = 0.f;
                for (int c = 0; c < 16; ++c)
                    v += W1[k * 128 + h * 16 + c] * ad1w[h * 16 + c];
            }
            Wt1[j * 128 + k] = (u16)bf16rne(v);
        } else if (i < W1EXT * 128 + W2EXT * 128) {
            const int i2 = i - W1EXT * 128;
            const int j = i2 >> 7, k = i2 & 127;
            float v = 0.f;
            if (j < 64) {
                v = W2[k * 64 + j];
            } else if (j == 64) {
                for (int c = 0; c < 64; ++c) v += W2[k * 64 + c] * as2w[c];
            } else if (j == 65) {
                for (int c = 0; c < 64; ++c) v += W2[k * 64 + c] * ad2w[c];
            }
            Wt2[j * 128 + k] = (u16)bf16rne(v);
        }
        return;
    }

    // ---- binning path ----
    const int e0 = blockIdx.x * EPB;
    for (int i = t; i < NB; i += 256) lcnt[i] = 0;
    __syncthreads();

    for (int i = t; i < EPB; i += 256) {
        const int e = e0 + i;
        if (e >= NE) break;
        const int src = ei[e];
        const int dst = ei[NE + e];
        const int b = dst >> 8;
        const int p = atomicAdd(&lcnt[b], 1);       // LDS atomic (cheap)
        lbuf[b * LCAP + p] = ((u32)(dst & 255) << 16) | (u32)src;
    }
    __syncthreads();

    for (int i = t; i < NB; i += 256)
        gbase[i] = atomicAdd(&cnt[i * CPAD], lcnt[i]);
    __syncthreads();

    // flush: thread = bucket; sequential stores -> lines merge in L2
    for (int b = t; b < NB; b += 256) {
        const int n = lcnt[b];
        const int gb = gbase[b];
        u32* dstp = staging + (size_t)b * CAPB + gb;
        const u32* srcp = lbuf + b * LCAP;
        for (int j = 0; j < n; ++j) dstp[j] = srcp[j];
    }
}

// ---------------------------------------------------------------------------
// Fused launch 2: blocks 0..NB-1 = k_place (CSR build, 8-padded rows, fixed
// bucket base); blocks NB.. = MFMA GEMM1 [h1|as1|ad1] = x @ W1ext, 128 rows x
// 8 waves. h1 is stored in FP8 e4m3 (128 B/row): fragments -> swizzled LDS
// bytes -> coalesced uint4 stores. Alphas stay fp32 flat [row*NH+h].
// ---------------------------------------------------------------------------
__global__ __launch_bounds__(512) void k_place_gemm1(
    const int* __restrict__ cnt, const u32* __restrict__ staging,
    int* __restrict__ rowptr, int* __restrict__ rowend,
    u16* __restrict__ sorted16,
    const float* __restrict__ x, const u16* __restrict__ Wt1,
    u32* __restrict__ h1f8, float* __restrict__ as1, float* __restrict__ ad1)
{
    __shared__ u32 xb[128 * 64];     // 32 KB (gemm: A tile, then C staging)
    __shared__ u32 Wb[W1EXT * 64];   // 36 KB
    const int tid = threadIdx.x;

    if (blockIdx.x < NB) {
        // ---- place path (512 threads; LDS carved from xb) ----
        int* hist = (int*)xb;
        int* cur  = hist + 256;
        int* scan = cur + 256;
        const int b = blockIdx.x;
        const int tot = cnt[b * CPAD];
        const int base = b * BSTRIDE;

        if (tid < 256) hist[tid] = ((b * 256 + tid) < NN) ? 1 : 0;  // self-loop
        __syncthreads();

        for (int i = tid; i < tot; i += 512)
            atomicAdd(&hist[staging[(size_t)b * CAPB + i] >> 16], 1);
        __syncthreads();

        if (tid < 256) scan[tid] = (hist[tid] + 7) & ~7;   // pad8 counts
        __syncthreads();
        for (int off = 1; off < 256; off <<= 1) {
            int v = 0;
            if (tid < 256 && tid >= off) v = scan[tid - off];
            __syncthreads();
            if (tid < 256) scan[tid] += v;
            __syncthreads();
        }
        if (tid < 256) {
            const int padded = (hist[tid] + 7) & ~7;
            const int excl = (tid == 0) ? 0 : scan[tid - 1];
            const int node = b * 256 + tid;
            if (node < NN) {
                rowptr[node] = base + excl;
                rowend[node] = base + excl + padded;       // padded end
                sorted16[base + excl] = (u16)node;         // self-loop first
                for (int j = hist[tid]; j < padded; ++j)   // null-pad tail
                    sorted16[base + excl + j] = (u16)NN;
                cur[tid] = excl + 1;
            } else {
                cur[tid] = excl;
            }
        }
        __syncthreads();
        for (int i = tid; i < tot; i += 512) {
            const u32 v = staging[(size_t)b * CAPB + i];
            const int pos = atomicAdd(&cur[v >> 16], 1);
            sorted16[base + pos] = (u16)(v & 0xffffu);
        }
        return;
    }

    // ---- gemm1 path ----
    const int row0 = (blockIdx.x - NB) * 128;

    {   // stage Wb from Wt1 (bf16 [j][k]): 2304 chunks over 512 threads
        const uint4* Wt = (const uint4*)Wt1;
        for (int p = 0; p < 5; ++p) {
            const int id = p * 512 + tid;
            if (id < W1EXT * 16) {
                const int n = id >> 4, c = id & 15;
                *(uint4*)(Wb + n * 64 + ((c ^ (n & 15)) << 2)) = Wt[n * 16 + c];
            }
        }
    }
    for (int p = 0; p < 4; ++p) {    // 2048 chunks of xb
        const int id = p * 512 + tid;
        const int m = id >> 4, c = id & 15;
        const int row = row0 + m;
        uint4 v = make_uint4(0, 0, 0, 0);
        if (row < NN) {
            const float4 f0 = *(const float4*)(x + (size_t)row * 128 + c * 8);
            const float4 f1 = *(const float4*)(x + (size_t)row * 128 + c * 8 + 4);
            v.x = bf16rne(f0.x) | (bf16rne(f0.y) << 16);
            v.y = bf16rne(f0.z) | (bf16rne(f0.w) << 16);
            v.z = bf16rne(f1.x) | (bf16rne(f1.y) << 16);
            v.w = bf16rne(f1.z) | (bf16rne(f1.w) << 16);
        }
        *(uint4*)(xb + m * 64 + ((c ^ (m & 15)) << 2)) = v;
    }
    __syncthreads();

    const int w = tid >> 6, lane = tid & 63;   // w = 0..7 -> rows 16w..16w+15
    const int nl = lane & 15, quad = lane >> 4;
    f32x4 acc[9] = {};
    for (int kk = 0; kk < 4; ++kk) {
        const int cm = kk * 4 + quad;
        const bf16x8 a = *(const bf16x8*)(xb + (16 * w + nl) * 64 + ((cm ^ nl) << 2));
#pragma unroll
        for (int tn = 0; tn < 9; ++tn) {
            const bf16x8 b = *(const bf16x8*)(Wb + (16 * tn + nl) * 64 + ((cm ^ nl) << 2));
            acc[tn] = __builtin_amdgcn_mfma_f32_16x16x32_bf16(a, b, acc[tn], 0, 0, 0);
        }
    }

    __syncthreads();                 // all xb reads done -> reuse as C staging
    {   // h1 fragments -> fp8 bytes in LDS [128 rows][8 chunks of 16B],
        // chunk index XOR-swizzled by (row>>2)&7 -> <=4-way bank conflict
        u8* h1ld = (u8*)xb;
#pragma unroll
        for (int tn = 0; tn < 8; ++tn) {
#pragma unroll
            for (int r = 0; r < 4; ++r) {
                const int row = 16 * w + quad * 4 + r;
                const u32 pk = __builtin_amdgcn_cvt_pk_fp8_f32(
                    acc[tn][r], 0.f, 0u, false);   // byte0 = fp8(acc)
                h1ld[row * 128 + ((tn ^ ((row >> 2) & 7)) << 4) + nl] = (u8)pk;
            }
        }
    }
#pragma unroll
    for (int r = 0; r < 4; ++r) {    // tile 8: cols 128..143 = [as1 | ad1]
        const int row = row0 + 16 * w + quad * 4 + r;
        if (row < NN) {
            const float v = acc[8][r];
            if (nl < 8) as1[row * NH + nl] = v;
            else        ad1[row * NH + (nl - 8)] = v;
        }
    }
    __syncthreads();
    // coalesced fp8 h1 store: 1024 uint4 chunks, 2 per thread (unswizzle)
    for (int p = 0; p < 2; ++p) {
        const int id = p * 512 + tid;
        const int row = id >> 3, c = id & 7;
        const int grow = row0 + row;
        if (grow < NN)
            ((uint4*)h1f8)[(size_t)grow * 8 + c] =
                ((const uint4*)xb)[row * 8 + (c ^ ((row >> 2) & 7))];
    }
}

// ---------------------------------------------------------------------------
// MFMA GEMM2: [h2 | as2 | ad2] = act2 @ W2ext (50000x128 @ 128x80).
// h2 stays bf16 (feeds the final logits directly).
// ---------------------------------------------------------------------------
__global__ __launch_bounds__(512) void k_gemm2(
    const u32* __restrict__ act2b, const u16* __restrict__ Wt2,
    u16* __restrict__ h2s, float* __restrict__ as2, float* __restrict__ ad2)
{
    __shared__ u32 xb[128 * 64];     // 32 KB
    __shared__ u32 Wb[W2EXT * 64];   // 20 KB
    const int tid = threadIdx.x;
    const int row0 = blockIdx.x * 128;

    {   // stage Wb from Wt2: 1280 chunks over 512 threads
        const uint4* Wt = (const uint4*)Wt2;
        for (int p = 0; p < 3; ++p) {
            const int id = p * 512 + tid;
            if (id < W2EXT * 16) {
                const int n = id >> 4, c = id & 15;
                *(uint4*)(Wb + n * 64 + ((c ^ (n & 15)) << 2)) = Wt[n * 16 + c];
            }
        }
    }
    for (int p = 0; p < 4; ++p) {    // 2048 chunks of xb (bf16 row-major input)
        const int id = p * 512 + tid;
        const int m = id >> 4, c = id & 15;
        const int row = row0 + m;
        uint4 v = make_uint4(0, 0, 0, 0);
        if (row < NN) v = ((const uint4*)act2b)[(size_t)row * 16 + c];
        *(uint4*)(xb + m * 64 + ((c ^ (m & 15)) << 2)) = v;
    }
    __syncthreads();

    const int w = tid >> 6, lane = tid & 63;
    const int nl = lane & 15, quad = lane >> 4;
    f32x4 acc[5] = {};
    for (int kk = 0; kk < 4; ++kk) {
        const int cm = kk * 4 + quad;
        const bf16x8 a = *(const bf16x8*)(xb + (16 * w + nl) * 64 + ((cm ^ nl) << 2));
#pragma unroll
        for (int tn = 0; tn < 5; ++tn) {
            const bf16x8 b = *(const bf16x8*)(Wb + (16 * tn + nl) * 64 + ((cm ^ nl) << 2));
            acc[tn] = __builtin_amdgcn_mfma_f32_16x16x32_bf16(a, b, acc[tn], 0, 0, 0);
        }
    }

    __syncthreads();                 // all xb reads done -> reuse as C staging
    {   // h2 fragments -> LDS row-major u16 [128][64]
        u16* h2ld = (u16*)xb;
#pragma unroll
        for (int tn = 0; tn < 4; ++tn) {
#pragma unroll
            for (int r = 0; r < 4; ++r) {
                const int row = 16 * w + quad * 4 + r;
                h2ld[row * 64 + 16 * tn + nl] = (u16)bf16rne(acc[tn][r]);
            }
        }
    }
#pragma unroll
    for (int r = 0; r < 4; ++r) {    // tile 4: col 64 = as2, col 65 = ad2
        const int row = row0 + 16 * w + quad * 4 + r;
        if (row < NN) {
            const float v = acc[4][r];
            if (nl == 0) as2[row] = v;
            else if (nl == 1) ad2[row] = v;
        }
    }
    __syncthreads();
    // coalesced h2 store: 1024 uint4 chunks, 2 per thread
    for (int p = 0; p < 2; ++p) {
        const int id = p * 512 + tid;
        const int row = id >> 3, c = id & 7;
        const int grow = row0 + row;
        if (grow < NN)
            ((uint4*)h2s)[(size_t)grow * 8 + c] = ((const uint4*)xb)[row * 8 + c];
    }
}

// ---------------------------------------------------------------------------
// Aggregation layer 1 (narrow, fp8 rows, VALU-trimmed): one node per wave.
// Per 8-edge group: 1 uint4 pack, lane-split exp (lane j*8+h computes
// w(edge j, head h)) with den accumulated on the EXP lane (1 add/group vs 8),
// 8 per-lane u16 gathers (2-stage pipeline = 16 rows in flight), bpermute +
// fp8->f32x2 cvt + packed FMA (f32x2 acc, splat weight -> v_pk_fma_f32).
// Final den: shfl_xor tree over the j-replicas + 1 bpermute (h4).
// ---------------------------------------------------------------------------
#define PG1(KK, S, G, WJ) do {                                                \
    const uint4 p = *(const uint4*)(sorted16 + (KK));                         \
    S[0] = p.x & 0xffffu; S[1] = p.x >> 16;                                   \
    S[2] = p.y & 0xffffu; S[3] = p.y >> 16;                                   \
    S[4] = p.z & 0xffffu; S[5] = p.z >> 16;                                   \
    S[6] = p.w & 0xffffu; S[7] = p.w >> 16;                                   \
    const u32 hlf = (head & 4) ? ((head & 2) ? p.w : p.z)                     \
                               : ((head & 2) ? p.y : p.x);                    \
    const u32 sj = (head & 1) ? (hlf >> 16) : (hlf & 0xffffu);                \
    WJ = __expf(LR(as1[sj * NH + eh] + adeh));                                \
    denacc += WJ;                                                             \
    _Pragma("unroll") for (int j = 0; j < 8; ++j)                             \
        G[j] = h1u16[S[j] * 64 + lane];                                       \
} while (0)

#define CONS1(G, WJ) do {                                                     \
    _Pragma("unroll") for (int j = 0; j < 8; ++j) {                           \
        const float wv = __uint_as_float((u32)__builtin_amdgcn_ds_bpermute(   \
            h4 + j * 32, (int)__float_as_uint(WJ)));                          \
        const f32x2 f = __builtin_amdgcn_cvt_pk_f32_fp8((u32)G[j], false);    \
        acc2 += f * wv; }                                                     \
} while (0)

__global__ __launch_bounds__(256) void k_agg1(
    const int* __restrict__ rowptr, const int* __restrict__ rowend,
    const u16* __restrict__ sorted16,
    const u16* __restrict__ h1u16, const float* __restrict__ as1,
    const float* __restrict__ ad1,
    u32* __restrict__ act2b)
{
    const int node = blockIdx.x * 4 + (threadIdx.x >> 6);
    const int lane = threadIdx.x & 63;
    const int head = lane >> 3;          // accumulation head (channels 16h..)
    const int eh   = lane & 7;           // exp-role head
    const float adeh = ad1[node * NH + eh];
    const int k0 = rowptr[node], kend = rowend[node];   // multiple of 8, >=8
    const int h4 = head << 2;
    f32x2 acc2 = {0.f, 0.f};
    float denacc = 0.f;
    u32 sA[8], sB[8];
    u16 gA[8], gB[8];
    float wA, wB;

    PG1(k0, sA, gA, wA);
    int k = k0 + 8;
    while (k + 16 <= kend) {
        PG1(k, sB, gB, wB);      CONS1(gA, wA);
        PG1(k + 8, sA, gA, wA);  CONS1(gB, wB);
        k += 16;
    }
    if (k < kend) {
        PG1(k, sB, gB, wB);  CONS1(gA, wA);  CONS1(gB, wB);
    } else {
        CONS1(gA, wA);
    }

    // den: lane s holds partial sum of w(j=s>>3, h=s&7); reduce over j
    denacc += __shfl_xor(denacc, 8);
    denacc += __shfl_xor(denacc, 16);
    denacc += __shfl_xor(denacc, 32);
    // den of my accumulation head lives at lane (head) (that lane's s&7==head)
    const float den = __uint_as_float((u32)__builtin_amdgcn_ds_bpermute(
        h4, (int)__float_as_uint(denacc)));

    const float inv = 1.f / den;                    // self-loop => den > 0
    float v0 = acc2.x * inv, v1 = acc2.y * inv;
    v0 = v0 > 0.f ? v0 : expm1f(v0);                // ELU
    v1 = v1 > 0.f ? v1 : expm1f(v1);
    act2b[node * 64 + lane] = bf16rne(v0) | (bf16rne(v1) << 16);
}

// ---------------------------------------------------------------------------
// Aggregation layer 2 (narrow, VALU-trimmed) + log_softmax: one node per
// wave, lane = channel. Lane l computes w(edge l&7) and accumulates den
// locally (1 add/group); final den = shfl_xor 1/2/4 (every 8-lane group
// holds all 8 edge weights). bpermute broadcasts w for the FMA path.
// ---------------------------------------------------------------------------
#define PG2(KK, S, G, WJ) do {                                                \
    const uint4 p = *(const uint4*)(sorted16 + (KK));                         \
    S[0] = p.x & 0xffffu; S[1] = p.x >> 16;                                   \
    S[2] = p.y & 0xffffu; S[3] = p.y >> 16;                                   \
    S[4] = p.z & 0xffffu; S[5] = p.z >> 16;                                   \
    S[6] = p.w & 0xffffu; S[7] = p.w >> 16;                                   \
    const u32 hlf2 = (lane & 4) ? ((lane & 2) ? p.w : p.z)                    \
                                : ((lane & 2) ? p.y : p.x);                   \
    const u32 sj = (lane & 1) ? (hlf2 >> 16) : (hlf2 & 0xffffu);              \
    WJ = __expf(LR(as2[sj] + adv));                                           \
    denacc += WJ;                                                             \
    _Pragma("unroll") for (int j = 0; j < 8; ++j)                             \
        G[j] = h2s[S[j] * 64 + lane];                                         \
} while (0)

#define CONS2(G, WJ) do {                                                     \
    _Pragma("unroll") for (int j = 0; j < 8; ++j) {                           \
        const float wv = __uint_as_float((u32)__builtin_amdgcn_ds_bpermute(   \
            j << 2, (int)__float_as_uint(WJ)));                               \
        acc += wv * __uint_as_float(((u32)G[j]) << 16); }                     \
} while (0)

__global__ __launch_bounds__(256) void k_agg2(
    const int* __restrict__ rowptr, const int* __restrict__ rowend,
    const u16* __restrict__ sorted16,
    const u16* __restrict__ h2s, const float* __restrict__ as2,
    const float* __restrict__ ad2,
    float* __restrict__ out)
{
    const int node = blockIdx.x * 4 + (threadIdx.x >> 6);
    const int lane = threadIdx.x & 63;
    const float adv = ad2[node];
    const int k0 = rowptr[node], kend = rowend[node];
    float acc = 0.f, denacc = 0.f;
    u32 sA[8], sB[8];
    u16 gA[8], gB[8];
    float wA, wB;

    PG2(k0, sA, gA, wA);
    int k = k0 + 8;
    while (k + 16 <= kend) {
        PG2(k, sB, gB, wB);      CONS2(gA, wA);
        PG2(k + 8, sA, gA, wA);  CONS2(gB, wB);
        k += 16;
    }
    if (k < kend) {
        PG2(k, sB, gB, wB);  CONS2(gA, wA);  CONS2(gB, wB);
    } else {
        CONS2(gA, wA);
    }

    // den: each 8-lane group holds each edge's weight exactly once
    denacc += __shfl_xor(denacc, 1);
    denacc += __shfl_xor(denacc, 2);
    denacc += __shfl_xor(denacc, 4);

    const float v = acc / denacc;
    float m = v;
    for (int kk = 1; kk < 64; kk <<= 1) m = fmaxf(m, __shfl_xor(m, kk));
    float se = __expf(v - m);
    for (int kk = 1; kk < 64; kk <<= 1) se += __shfl_xor(se, kk);
    out[node * 64 + lane] = v - m - logf(se);
}

// ---------------------------------------------------------------------------
// Workspace layout (u32 units, 64B-aligned chunks).
// ---------------------------------------------------------------------------
extern "C" void kernel_launch(void* const* d_in, const int* in_sizes, int n_in,
                              void* d_out, int out_size, void* d_ws, size_t ws_size,
                              hipStream_t stream)
{
    (void)in_sizes; (void)n_in; (void)out_size; (void)ws_size;
    const float* x    = (const float*)d_in[0];
    const int*   ei   = (const int*)d_in[1];
    const float* W1   = (const float*)d_in[2];
    const float* as1w = (const float*)d_in[3];
    const float* ad1w = (const float*)d_in[4];
    const float* W2   = (const float*)d_in[6];
    const float* as2w = (const float*)d_in[7];
    const float* ad2w = (const float*)d_in[8];
    float* out = (float*)d_out;

    u32* ws = (u32*)d_ws;
    size_t o = 0;
    auto take = [&](size_t n) { size_t r = o; o += (n + 15) & ~(size_t)15; return r; };

    u32*   h1f8     = ws + take((size_t)32 * (NN + 1));    // fp8 rows, 128 B each
    float* as1      = (float*)(ws + take((size_t)NH * NN + 8));
    float* ad1      = (float*)(ws + take((size_t)NH * NN));
    u32*   act2b    = ws + take((size_t)64 * NN);          // bf16x2 packed
    float* as2      = (float*)(ws + take(NN + 1));
    float* ad2      = (float*)(ws + take(NN));
    int*   rowptr   = (int*)(ws + take(NN));
    int*   rowend   = (int*)(ws + take(NN));
    u16*   sorted16 = (u16*)(ws + take(((size_t)NB * BSTRIDE + 1) / 2));
    u32*   staging  = ws + take((size_t)NB * CAPB);
    int*   cnt      = (int*)(ws + take(NB * CPAD));
    u16*   Wt1      = (u16*)(ws + take((size_t)W1EXT * 128 / 2));
    u16*   Wt2      = (u16*)(ws + take((size_t)W2EXT * 128 / 2));
    u16*   h1u16    = (u16*)h1f8;          // fp8-pair view for agg1
    u16*   h2s      = (u16*)h1f8;          // alias (h1 dead after agg1)

    hipMemsetAsync(cnt, 0, NB * CPAD * sizeof(int), stream);

    k_prep_bin<<<NBB + WPB, 256, 0, stream>>>(
        ei, cnt, staging, W1, W2, as1w, ad1w, as2w, ad2w,
        Wt1, Wt2, h1f8, as1, as2);

    k_place_gemm1<<<NB + G1B, 512, 0, stream>>>(
        cnt, staging, rowptr, rowend, sorted16, x, Wt1, h1f8, as1, ad1);

    k_agg1<<<NN / 4, 256, 0, stream>>>(rowptr, rowend, sorted16, h1u16, as1, ad1, act2b);
    k_gemm2<<<G1B, 512, 0, stream>>>(act2b, Wt2, h2s, as2, ad2);
    k_agg2<<<NN / 4, 256, 0, stream>>>(rowptr, rowend, sorted16, h2s, as2, ad2, out);
}

// Round 14
// 173.078 us; speedup vs baseline: 1.1208x; 1.0095x over previous
//
#include <hip/hip_runtime.h>
#include <math.h>

typedef unsigned int  u32;
typedef unsigned short u16;
typedef unsigned char u8;
typedef short bf16x8 __attribute__((ext_vector_type(8)));   // 8 bf16 = 4 VGPRs
typedef float f32x4  __attribute__((ext_vector_type(4)));
typedef float f32x2  __attribute__((ext_vector_type(2)));

// Problem constants (match reference)
#define NN    50000
#define NE    800000
#define ET    (NE + NN)     // edges + self loops = 850000
#define IND   128
#define HIDD  128
#define NH    8
#define OD    64
#define SLOPE 0.2f

// Binned counting sort parameters. Self-loops are NOT staged (deterministic,
// k_place inserts them directly). Rows are padded to 8-edge groups with a
// NULL node (id NN, weight exactly 0) -> no tail loops, uint4 packs.
#define NB    196           // buckets of 256 nodes: ceil(50000/256)
#define EPB   4096          // edges per binning block
#define NBB   ((NE + EPB - 1) / EPB)   // 196 binning blocks (random edges only)
#define LCAP  64            // LDS cap per (block,bucket): mean 21, +9.4 sigma
#define CAPB  5120          // global cap per bucket: mean 4082, +13 sigma
#define CPAD  16            // counter stride in ints (64 B = own cache line)
#define BSTRIDE 7168        // fixed padded bucket stride (pad8)

// Extended GEMM widths: alpha reductions folded in as extra columns.
#define W1EXT 144
#define W2EXT 80
#define WPB   112           // wprep blocks (covers (W1EXT+W2EXT)*128 = 28672)
#define G1B   391           // gemm blocks: ceil(50000/128)

// bf16 round-to-nearest-even, returns low 16 bits
__device__ __forceinline__ u32 bf16rne(float f) {
    u32 u = __float_as_uint(f);
    return (u + 0x7fffu + ((u >> 16) & 1u)) >> 16;
}

// leaky_relu(s) == max(s, SLOPE*s) for 0 < SLOPE < 1
#define LR(s) fmaxf((s), SLOPE * (s))

// ---------------------------------------------------------------------------
// Fused launch 1: blocks 0..NBB-1 = edge binning (LDS-staged radix partition);
// blocks NBB.. = weight prep (extended transposed bf16 weights + null inits).
// cnt is zeroed by hipMemsetAsync before this launch (bin atomics need it).
// ---------------------------------------------------------------------------
__global__ __launch_bounds__(256) void k_prep_bin(
    const int* __restrict__ ei, int* __restrict__ cnt, u32* __restrict__ staging,
    const float* __restrict__ W1, const float* __restrict__ W2,
    const float* __restrict__ as1w, const float* __restrict__ ad1w,
    const float* __restrict__ as2w, const float* __restrict__ ad2w,
    u16* __restrict__ Wt1, u16* __restrict__ Wt2,
    u32* __restrict__ h1f8, float* __restrict__ as1, float* __restrict__ as2)
{
    __shared__ u32 lbuf[NB * LCAP];   // 50176 B (bin path only)
    __shared__ int lcnt[NB];
    __shared__ int gbase[NB];
    const int t = threadIdx.x;

    if (blockIdx.x >= NBB) {
        // ---- weight-prep path ----
        const int i = (blockIdx.x - NBB) * 256 + t;
        if (i < 32) h1f8[(size_t)NN * 32 + i] = 0;         // null h1 row (fp8 0)
        if (i < 8)  as1[(size_t)NH * NN + i] = -1e30f;     // null alpha_src L1
        if (i == 8) as2[NN] = -1e30f;                      // null alpha_src L2

        if (i < W1EXT * 128) {
            const int j = i >> 7, k = i & 127;
            float v;
            if (j < 128) {
                v = W1[k * 128 + j];
            } else if (j < 136) {
                const int h = j - 128;
                v = 0.f;
                for (int c = 0; c < 16; ++c)
                    v += W1[k * 128 + h * 16 + c] * as1w[h * 16 + c];
            } else {
                const int h = j - 136;
                v = 0.f;
                for (int c = 0; c < 16; ++c)
                    v += W1[k * 128 + h * 16 + c] * ad1w[h * 16 + c];
            }
            Wt1[j * 128 + k] = (u16)bf16rne(v);
        } else if (i < W1EXT * 128 + W2EXT * 128) {
            const int i2 = i - W1EXT * 128;
            const int j = i2 >> 7, k = i2 & 127;
            float v = 0.f;
            if (j < 64) {
                v = W2[k * 64 + j];
            } else if (j == 64) {
                for (int c = 0; c < 64; ++c) v += W2[k * 64 + c] * as2w[c];
            } else if (j == 65) {
                for (int c = 0; c < 64; ++c) v += W2[k * 64 + c] * ad2w[c];
            }
            Wt2[j * 128 + k] = (u16)bf16rne(v);
        }
        return;
    }

    // ---- binning path ----
    const int e0 = blockIdx.x * EPB;
    for (int i = t; i < NB; i += 256) lcnt[i] = 0;
    __syncthreads();

    for (int i = t; i < EPB; i += 256) {
        const int e = e0 + i;
        if (e >= NE) break;
        const int src = ei[e];
        const int dst = ei[NE + e];
        const int b = dst >> 8;
        const int p = atomicAdd(&lcnt[b], 1);       // LDS atomic (cheap)
        lbuf[b * LCAP + p] = ((u32)(dst & 255) << 16) | (u32)src;
    }
    __syncthreads();

    for (int i = t; i < NB; i += 256)
        gbase[i] = atomicAdd(&cnt[i * CPAD], lcnt[i]);
    __syncthreads();

    // flush: thread = bucket; sequential stores -> lines merge in L2
    for (int b = t; b < NB; b += 256) {
        const int n = lcnt[b];
        const int gb = gbase[b];
        u32* dstp = staging + (size_t)b * CAPB + gb;
        const u32* srcp = lbuf + b * LCAP;
        for (int j = 0; j < n; ++j) dstp[j] = srcp[j];
    }
}

// ---------------------------------------------------------------------------
// Fused launch 2: blocks 0..NB-1 = k_place (CSR build, 8-padded rows, fixed
// bucket base); blocks NB.. = MFMA GEMM1 [h1|as1|ad1] = x @ W1ext, 128 rows x
// 8 waves. h1 is stored in FP8 e4m3 (128 B/row): fragments -> swizzled LDS
// bytes -> coalesced uint4 stores. Alphas stay fp32 flat [row*NH+h].
// ---------------------------------------------------------------------------
__global__ __launch_bounds__(512) void k_place_gemm1(
    const int* __restrict__ cnt, const u32* __restrict__ staging,
    int* __restrict__ rowptr, int* __restrict__ rowend,
    u16* __restrict__ sorted16,
    const float* __restrict__ x, const u16* __restrict__ Wt1,
    u32* __restrict__ h1f8, float* __restrict__ as1, float* __restrict__ ad1)
{
    __shared__ u32 xb[128 * 64];     // 32 KB (gemm: A tile, then C staging)
    __shared__ u32 Wb[W1EXT * 64];   // 36 KB
    const int tid = threadIdx.x;

    if (blockIdx.x < NB) {
        // ---- place path (512 threads; LDS carved from xb) ----
        int* hist = (int*)xb;
        int* cur  = hist + 256;
        int* scan = cur + 256;
        const int b = blockIdx.x;
        const int tot = cnt[b * CPAD];
        const int base = b * BSTRIDE;

        if (tid < 256) hist[tid] = ((b * 256 + tid) < NN) ? 1 : 0;  // self-loop
        __syncthreads();

        for (int i = tid; i < tot; i += 512)
            atomicAdd(&hist[staging[(size_t)b * CAPB + i] >> 16], 1);
        __syncthreads();

        if (tid < 256) scan[tid] = (hist[tid] + 7) & ~7;   // pad8 counts
        __syncthreads();
        for (int off = 1; off < 256; off <<= 1) {
            int v = 0;
            if (tid < 256 && tid >= off) v = scan[tid - off];
            __syncthreads();
            if (tid < 256) scan[tid] += v;
            __syncthreads();
        }
        if (tid < 256) {
            const int padded = (hist[tid] + 7) & ~7;
            const int excl = (tid == 0) ? 0 : scan[tid - 1];
            const int node = b * 256 + tid;
            if (node < NN) {
                rowptr[node] = base + excl;
                rowend[node] = base + excl + padded;       // padded end
                sorted16[base + excl] = (u16)node;         // self-loop first
                for (int j = hist[tid]; j < padded; ++j)   // null-pad tail
                    sorted16[base + excl + j] = (u16)NN;
                cur[tid] = excl + 1;
            } else {
                cur[tid] = excl;
            }
        }
        __syncthreads();
        for (int i = tid; i < tot; i += 512) {
            const u32 v = staging[(size_t)b * CAPB + i];
            const int pos = atomicAdd(&cur[v >> 16], 1);
            sorted16[base + pos] = (u16)(v & 0xffffu);
        }
        return;
    }

    // ---- gemm1 path ----
    const int row0 = (blockIdx.x - NB) * 128;

    {   // stage Wb from Wt1 (bf16 [j][k]): 2304 chunks over 512 threads
        const uint4* Wt = (const uint4*)Wt1;
        for (int p = 0; p < 5; ++p) {
            const int id = p * 512 + tid;
            if (id < W1EXT * 16) {
                const int n = id >> 4, c = id & 15;
                *(uint4*)(Wb + n * 64 + ((c ^ (n & 15)) << 2)) = Wt[n * 16 + c];
            }
        }
    }
    for (int p = 0; p < 4; ++p) {    // 2048 chunks of xb
        const int id = p * 512 + tid;
        const int m = id >> 4, c = id & 15;
        const int row = row0 + m;
        uint4 v = make_uint4(0, 0, 0, 0);
        if (row < NN) {
            const float4 f0 = *(const float4*)(x + (size_t)row * 128 + c * 8);
            const float4 f1 = *(const float4*)(x + (size_t)row * 128 + c * 8 + 4);
            v.x = bf16rne(f0.x) | (bf16rne(f0.y) << 16);
            v.y = bf16rne(f0.z) | (bf16rne(f0.w) << 16);
            v.z = bf16rne(f1.x) | (bf16rne(f1.y) << 16);
            v.w = bf16rne(f1.z) | (bf16rne(f1.w) << 16);
        }
        *(uint4*)(xb + m * 64 + ((c ^ (m & 15)) << 2)) = v;
    }
    __syncthreads();

    const int w = tid >> 6, lane = tid & 63;   // w = 0..7 -> rows 16w..16w+15
    const int nl = lane & 15, quad = lane >> 4;
    f32x4 acc[9] = {};
    for (int kk = 0; kk < 4; ++kk) {
        const int cm = kk * 4 + quad;
        const bf16x8 a = *(const bf16x8*)(xb + (16 * w + nl) * 64 + ((cm ^ nl) << 2));
#pragma unroll
        for (int tn = 0; tn < 9; ++tn) {
            const bf16x8 b = *(const bf16x8*)(Wb + (16 * tn + nl) * 64 + ((cm ^ nl) << 2));
            acc[tn] = __builtin_amdgcn_mfma_f32_16x16x32_bf16(a, b, acc[tn], 0, 0, 0);
        }
    }

    __syncthreads();                 // all xb reads done -> reuse as C staging
    {   // h1 fragments -> fp8 bytes in LDS [128 rows][8 chunks of 16B],
        // chunk index XOR-swizzled by (row>>2)&7 -> <=4-way bank conflict
        u8* h1ld = (u8*)xb;
#pragma unroll
        for (int tn = 0; tn < 8; ++tn) {
#pragma unroll
            for (int r = 0; r < 4; ++r) {
                const int row = 16 * w + quad * 4 + r;
                const u32 pk = __builtin_amdgcn_cvt_pk_fp8_f32(
                    acc[tn][r], 0.f, 0u, false);   // byte0 = fp8(acc)
                h1ld[row * 128 + ((tn ^ ((row >> 2) & 7)) << 4) + nl] = (u8)pk;
            }
        }
    }
#pragma unroll
    for (int r = 0; r < 4; ++r) {    // tile 8: cols 128..143 = [as1 | ad1]
        const int row = row0 + 16 * w + quad * 4 + r;
        if (row < NN) {
            const float v = acc[8][r];
            if (nl < 8) as1[row * NH + nl] = v;
            else        ad1[row * NH + (nl - 8)] = v;
        }
    }
    __syncthreads();
    // coalesced fp8 h1 store: 1024 uint4 chunks, 2 per thread (unswizzle)
    for (int p = 0; p < 2; ++p) {
        const int id = p * 512 + tid;
        const int row = id >> 3, c = id & 7;
        const int grow = row0 + row;
        if (grow < NN)
            ((uint4*)h1f8)[(size_t)grow * 8 + c] =
                ((const uint4*)xb)[row * 8 + (c ^ ((row >> 2) & 7))];
    }
}

// ---------------------------------------------------------------------------
// MFMA GEMM2: [h2 | as2 | ad2] = act2 @ W2ext (50000x128 @ 128x80).
// h2 stays bf16 (feeds the final logits directly).
// ---------------------------------------------------------------------------
__global__ __launch_bounds__(512) void k_gemm2(
    const u32* __restrict__ act2b, const u16* __restrict__ Wt2,
    u16* __restrict__ h2s, float* __restrict__ as2, float* __restrict__ ad2)
{
    __shared__ u32 xb[128 * 64];     // 32 KB
    __shared__ u32 Wb[W2EXT * 64];   // 20 KB
    const int tid = threadIdx.x;
    const int row0 = blockIdx.x * 128;

    {   // stage Wb from Wt2: 1280 chunks over 512 threads
        const uint4* Wt = (const uint4*)Wt2;
        for (int p = 0; p < 3; ++p) {
            const int id = p * 512 + tid;
            if (id < W2EXT * 16) {
                const int n = id >> 4, c = id & 15;
                *(uint4*)(Wb + n * 64 + ((c ^ (n & 15)) << 2)) = Wt[n * 16 + c];
            }
        }
    }
    for (int p = 0; p < 4; ++p) {    // 2048 chunks of xb (bf16 row-major input)
        const int id = p * 512 + tid;
        const int m = id >> 4, c = id & 15;
        const int row = row0 + m;
        uint4 v = make_uint4(0, 0, 0, 0);
        if (row < NN) v = ((const uint4*)act2b)[(size_t)row * 16 + c];
        *(uint4*)(xb + m * 64 + ((c ^ (m & 15)) << 2)) = v;
    }
    __syncthreads();

    const int w = tid >> 6, lane = tid & 63;
    const int nl = lane & 15, quad = lane >> 4;
    f32x4 acc[5] = {};
    for (int kk = 0; kk < 4; ++kk) {
        const int cm = kk * 4 + quad;
        const bf16x8 a = *(const bf16x8*)(xb + (16 * w + nl) * 64 + ((cm ^ nl) << 2));
#pragma unroll
        for (int tn = 0; tn < 5; ++tn) {
            const bf16x8 b = *(const bf16x8*)(Wb + (16 * tn + nl) * 64 + ((cm ^ nl) << 2));
            acc[tn] = __builtin_amdgcn_mfma_f32_16x16x32_bf16(a, b, acc[tn], 0, 0, 0);
        }
    }

    __syncthreads();                 // all xb reads done -> reuse as C staging
    {   // h2 fragments -> LDS row-major u16 [128][64]
        u16* h2ld = (u16*)xb;
#pragma unroll
        for (int tn = 0; tn < 4; ++tn) {
#pragma unroll
            for (int r = 0; r < 4; ++r) {
                const int row = 16 * w + quad * 4 + r;
                h2ld[row * 64 + 16 * tn + nl] = (u16)bf16rne(acc[tn][r]);
            }
        }
    }
#pragma unroll
    for (int r = 0; r < 4; ++r) {    // tile 4: col 64 = as2, col 65 = ad2
        const int row = row0 + 16 * w + quad * 4 + r;
        if (row < NN) {
            const float v = acc[4][r];
            if (nl == 0) as2[row] = v;
            else if (nl == 1) ad2[row] = v;
        }
    }
    __syncthreads();
    // coalesced h2 store: 1024 uint4 chunks, 2 per thread
    for (int p = 0; p < 2; ++p) {
        const int id = p * 512 + tid;
        const int row = id >> 3, c = id & 7;
        const int grow = row0 + row;
        if (grow < NN)
            ((uint4*)h2s)[(size_t)grow * 8 + c] = ((const uint4*)xb)[row * 8 + c];
    }
}

// ---------------------------------------------------------------------------
// Aggregation layer 1 (fp8, 2-edges-per-load): one node per wave. Lanes 0-31
// take even edges, 32-63 odd edges; lane covers a channel QUAD (4 fp8 ch) of
// its edge via ONE u32 load -> per 8-edge group: 4 loads, 4 bpermutes, 8
// cvt_pk, 8 pk-FMA (vs 8/8/8/8 on half the channels before). Component
// select of sorted16 pack is compile-time; only a 16-bit shift is runtime.
// Exp role unchanged (lane j*8+h computes w(edge j, head h); den on exp
// lane). shfl_xor(32) merges edge halves; lanes 0-31 store uint2.
// ---------------------------------------------------------------------------
#define PG1(KK, P, G, WJ) do {                                                \
    P = *(const uint4*)(sorted16 + (KK));                                     \
    const u32 hlf = (ej & 4) ? ((ej & 2) ? P.w : P.z)                         \
                             : ((ej & 2) ? P.y : P.x);                        \
    const u32 sj = (ej & 1) ? (hlf >> 16) : (hlf & 0xffffu);                  \
    WJ = __expf(LR(as1[sj * NH + eh] + adeh));                                \
    denacc += WJ;                                                             \
    const u32 s0 = (P.x >> hsh) & 0xffffu;                                    \
    const u32 s1 = (P.y >> hsh) & 0xffffu;                                    \
    const u32 s2 = (P.z >> hsh) & 0xffffu;                                    \
    const u32 s3 = (P.w >> hsh) & 0xffffu;                                    \
    G[0] = h1u32[(size_t)s0 * 32 + q];                                        \
    G[1] = h1u32[(size_t)s1 * 32 + q];                                        \
    G[2] = h1u32[(size_t)s2 * 32 + q];                                        \
    G[3] = h1u32[(size_t)s3 * 32 + q];                                        \
} while (0)

#define CONS1(G, WJ) do {                                                     \
    _Pragma("unroll") for (int i = 0; i < 4; ++i) {                           \
        const float wv = __uint_as_float((u32)__builtin_amdgcn_ds_bpermute(   \
            bpb + (i << 6), (int)__float_as_uint(WJ)));                       \
        const f32x2 flo = __builtin_amdgcn_cvt_pk_f32_fp8(G[i], false);       \
        const f32x2 fhi = __builtin_amdgcn_cvt_pk_f32_fp8(G[i], true);        \
        accA += flo * wv;                                                     \
        accB += fhi * wv; }                                                   \
} while (0)

__global__ __launch_bounds__(256) void k_agg1(
    const int* __restrict__ rowptr, const int* __restrict__ rowend,
    const u16* __restrict__ sorted16,
    const u32* __restrict__ h1u32, const float* __restrict__ as1,
    const float* __restrict__ ad1,
    u32* __restrict__ act2b)
{
    const int node = blockIdx.x * 4 + (threadIdx.x >> 6);
    const int lane = threadIdx.x & 63;
    const int ej = lane >> 3;            // exp role: edge index
    const int eh = lane & 7;             // exp role: head
    const float adeh = ad1[node * NH + eh];
    const int half = lane >> 5;          // gather role: edge parity
    const int hsh  = half << 4;          // u16 extract shift (0 or 16)
    const int q    = lane & 31;          // channel quad (4 fp8 channels)
    const int bpb  = (half << 5) | ((q >> 2) << 2);   // w(edge=half, head=q>>2)
    const int gh4  = (q >> 2) << 2;      // den bpermute addr (lane = my head)
    const int k0 = rowptr[node], kend = rowend[node];   // multiple of 8, >=8
    f32x2 accA = {0.f, 0.f}, accB = {0.f, 0.f};
    float denacc = 0.f;
    uint4 pA, pB;
    u32 gA[4], gB[4];
    float wA, wB;

    PG1(k0, pA, gA, wA);
    int k = k0 + 8;
    while (k + 16 <= kend) {
        PG1(k, pB, gB, wB);      CONS1(gA, wA);
        PG1(k + 8, pA, gA, wA);  CONS1(gB, wB);
        k += 16;
    }
    if (k < kend) {
        PG1(k, pB, gB, wB);  CONS1(gA, wA);  CONS1(gB, wB);
    } else {
        CONS1(gA, wA);
    }

    // den: lane s holds partial sum of w(j=s>>3, h=s&7); reduce over j
    denacc += __shfl_xor(denacc, 8);
    denacc += __shfl_xor(denacc, 16);
    denacc += __shfl_xor(denacc, 32);
    const float den = __uint_as_float((u32)__builtin_amdgcn_ds_bpermute(
        gh4, (int)__float_as_uint(denacc)));

    // merge edge halves: lanes l and l^32 share channel quad q
    accA.x += __shfl_xor(accA.x, 32);
    accA.y += __shfl_xor(accA.y, 32);
    accB.x += __shfl_xor(accB.x, 32);
    accB.y += __shfl_xor(accB.y, 32);

    const float inv = 1.f / den;                    // self-loop => den > 0
    float v0 = accA.x * inv, v1 = accA.y * inv;
    float v2 = accB.x * inv, v3 = accB.y * inv;
    v0 = v0 > 0.f ? v0 : expm1f(v0);                // ELU
    v1 = v1 > 0.f ? v1 : expm1f(v1);
    v2 = v2 > 0.f ? v2 : expm1f(v2);
    v3 = v3 > 0.f ? v3 : expm1f(v3);
    if (lane < 32) {                                // 32 lanes x 8 B = 256 B
        uint2 o;
        o.x = bf16rne(v0) | (bf16rne(v1) << 16);
        o.y = bf16rne(v2) | (bf16rne(v3) << 16);
        *(uint2*)(act2b + (size_t)node * 64 + q * 2) = o;
    }
}

// ---------------------------------------------------------------------------
// Aggregation layer 2 (bf16x2, 2-edges-per-load) + log_softmax: one node per
// wave. Lanes 0-31 even edges / 32-63 odd edges; lane covers a channel PAIR
// via ONE u32 load -> 4 loads + 4 bpermutes per 8-edge group (vs 8/8).
// Exp role: lane computes w(edge lane&7), den local + shfl 1/2/4.
// shfl_xor(32) merges halves; softmax over the 32-lane channel pairs.
// ---------------------------------------------------------------------------
#define PG2(KK, P, G, WJ) do {                                                \
    P = *(const uint4*)(sorted16 + (KK));                                     \
    const u32 hlf2 = (lane & 4) ? ((lane & 2) ? P.w : P.z)                    \
                                : ((lane & 2) ? P.y : P.x);                   \
    const u32 sj = (lane & 1) ? (hlf2 >> 16) : (hlf2 & 0xffffu);              \
    WJ = __expf(LR(as2[sj] + adv));                                           \
    denacc += WJ;                                                             \
    const u32 s0 = (P.x >> hsh) & 0xffffu;                                    \
    const u32 s1 = (P.y >> hsh) & 0xffffu;                                    \
    const u32 s2 = (P.z >> hsh) & 0xffffu;                                    \
    const u32 s3 = (P.w >> hsh) & 0xffffu;                                    \
    G[0] = h2u32[(size_t)s0 * 32 + chp];                                      \
    G[1] = h2u32[(size_t)s1 * 32 + chp];                                      \
    G[2] = h2u32[(size_t)s2 * 32 + chp];                                      \
    G[3] = h2u32[(size_t)s3 * 32 + chp];                                      \
} while (0)

#define CONS2(G, WJ) do {                                                     \
    _Pragma("unroll") for (int i = 0; i < 4; ++i) {                           \
        const float wv = __uint_as_float((u32)__builtin_amdgcn_ds_bpermute(   \
            bph + (i << 3), (int)__float_as_uint(WJ)));                       \
        acc2.x += wv * __uint_as_float(G[i] << 16);                           \
        acc2.y += wv * __uint_as_float(G[i] & 0xffff0000u); }                 \
} while (0)

__global__ __launch_bounds__(256) void k_agg2(
    const int* __restrict__ rowptr, const int* __restrict__ rowend,
    const u16* __restrict__ sorted16,
    const u32* __restrict__ h2u32, const float* __restrict__ as2,
    const float* __restrict__ ad2,
    float* __restrict__ out)
{
    const int node = blockIdx.x * 4 + (threadIdx.x >> 6);
    const int lane = threadIdx.x & 63;
    const float adv = ad2[node];
    const int half = lane >> 5;          // gather role: edge parity
    const int hsh  = half << 4;          // u16 extract shift
    const int chp  = lane & 31;          // channel pair (64 ch = 32 pairs)
    const int bph  = half << 2;          // w(edge=half) bpermute base
    const int k0 = rowptr[node], kend = rowend[node];
    f32x2 acc2 = {0.f, 0.f};
    float denacc = 0.f;
    uint4 pA, pB;
    u32 gA[4], gB[4];
    float wA, wB;

    PG2(k0, pA, gA, wA);
    int k = k0 + 8;
    while (k + 16 <= kend) {
        PG2(k, pB, gB, wB);      CONS2(gA, wA);
        PG2(k + 8, pA, gA, wA);  CONS2(gB, wB);
        k += 16;
    }
    if (k < kend) {
        PG2(k, pB, gB, wB);  CONS2(gA, wA);  CONS2(gB, wB);
    } else {
        CONS2(gA, wA);
    }

    // den: each 8-lane group holds each edge slot's weight exactly once
    denacc += __shfl_xor(denacc, 1);
    denacc += __shfl_xor(denacc, 2);
    denacc += __shfl_xor(denacc, 4);

    // merge edge halves: lanes l and l^32 share channel pair chp
    acc2.x += __shfl_xor(acc2.x, 32);
    acc2.y += __shfl_xor(acc2.y, 32);

    const float inv = 1.f / denacc;
    const float v0 = acc2.x * inv, v1 = acc2.y * inv;
    float m = fmaxf(v0, v1);
    m = fmaxf(m, __shfl_xor(m, 1));
    m = fmaxf(m, __shfl_xor(m, 2));
    m = fmaxf(m, __shfl_xor(m, 4));
    m = fmaxf(m, __shfl_xor(m, 8));
    m = fmaxf(m, __shfl_xor(m, 16));
    float se = __expf(v0 - m) + __expf(v1 - m);
    se += __shfl_xor(se, 1);
    se += __shfl_xor(se, 2);
    se += __shfl_xor(se, 4);
    se += __shfl_xor(se, 8);
    se += __shfl_xor(se, 16);
    const float lse = m + logf(se);
    if (lane < 32) {                     // 32 lanes x 8 B = 256 B/node
        float2 o = make_float2(v0 - lse, v1 - lse);
        *(float2*)(out + (size_t)node * 64 + chp * 2) = o;
    }
}

// ---------------------------------------------------------------------------
// Workspace layout (u32 units, 64B-aligned chunks).
// ---------------------------------------------------------------------------
extern "C" void kernel_launch(void* const* d_in, const int* in_sizes, int n_in,
                              void* d_out, int out_size, void* d_ws, size_t ws_size,
                              hipStream_t stream)
{
    (void)in_sizes; (void)n_in; (void)out_size; (void)ws_size;
    const float* x    = (const float*)d_in[0];
    const int*   ei   = (const int*)d_in[1];
    const float* W1   = (const float*)d_in[2];
    const float* as1w = (const float*)d_in[3];
    const float* ad1w = (const float*)d_in[4];
    const float* W2   = (const float*)d_in[6];
    const float* as2w = (const float*)d_in[7];
    const float* ad2w = (const float*)d_in[8];
    float* out = (float*)d_out;

    u32* ws = (u32*)d_ws;
    size_t o = 0;
    auto take = [&](size_t n) { size_t r = o; o += (n + 15) & ~(size_t)15; return r; };

    u32*   h1f8     = ws + take((size_t)32 * (NN + 1));    // fp8 rows, 128 B each
    float* as1      = (float*)(ws + take((size_t)NH * NN + 8));
    float* ad1      = (float*)(ws + take((size_t)NH * NN));
    u32*   act2b    = ws + take((size_t)64 * NN);          // bf16x2 packed
    float* as2      = (float*)(ws + take(NN + 1));
    float* ad2      = (float*)(ws + take(NN));
    int*   rowptr   = (int*)(ws + take(NN));
    int*   rowend   = (int*)(ws + take(NN));
    u16*   sorted16 = (u16*)(ws + take(((size_t)NB * BSTRIDE + 1) / 2));
    u32*   staging  = ws + take((size_t)NB * CAPB);
    int*   cnt      = (int*)(ws + take(NB * CPAD));
    u16*   Wt1      = (u16*)(ws + take((size_t)W1EXT * 128 / 2));
    u16*   Wt2      = (u16*)(ws + take((size_t)W2EXT * 128 / 2));
    u16*   h2s      = (u16*)h1f8;          // alias (h1 dead after agg1)
    u32*   h2u32    = h1f8;                // u32 (bf16-pair) view for agg2

    hipMemsetAsync(cnt, 0, NB * CPAD * sizeof(int), stream);

    k_prep_bin<<<NBB + WPB, 256, 0, stream>>>(
        ei, cnt, staging, W1, W2, as1w, ad1w, as2w, ad2w,
        Wt1, Wt2, h1f8, as1, as2);

    k_place_gemm1<<<NB + G1B, 512, 0, stream>>>(
        cnt, staging, rowptr, rowend, sorted16, x, Wt1, h1f8, as1, ad1);

    k_agg1<<<NN / 4, 256, 0, stream>>>(rowptr, rowend, sorted16, h1f8, as1, ad1, act2b);
    k_gemm2<<<G1B, 512, 0, stream>>>(act2b, Wt2, h2s, as2, ad2);
    k_agg2<<<NN / 4, 256, 0, stream>>>(rowptr, rowend, sorted16, h2u32, as2, ad2, out);
}